// Round 3
// baseline (1345.177 us; speedup 1.0000x reference)
//
#include <hip/hip_runtime.h>
#include <hip/hip_bf16.h>

#define NP 128      // pathways
#define NV 128      // vars per pathway
#define NW 64       // hidden width
#define NB 16384    // batch
#define TB 128      // batch tile per block
#define BN_EPS 1e-5f

typedef __attribute__((ext_vector_type(8))) short short8;
typedef __attribute__((ext_vector_type(4))) float f32x4;

__device__ __forceinline__ unsigned short f2bf(float f) {
    // round-to-nearest-even fp32 -> bf16
    unsigned int u = __float_as_uint(f);
    u += 0x7fffu + ((u >> 16) & 1u);
    return (unsigned short)(u >> 16);
}

__device__ __forceinline__ short8 pack8(const float4& a, const float4& b) {
    short8 r;
    r[0] = (short)f2bf(a.x); r[1] = (short)f2bf(a.y);
    r[2] = (short)f2bf(a.z); r[3] = (short)f2bf(a.w);
    r[4] = (short)f2bf(b.x); r[5] = (short)f2bf(b.y);
    r[6] = (short)f2bf(b.z); r[7] = (short)f2bf(b.w);
    return r;
}

// ---------------------------------------------------------------------------
// Kernel 1: per-pathway fused 2-layer MLP.
//   p[b,j] = leaky( leaky(x[b,j,:] @ W1[j]^T) @ W2[j] )
// One block = one pathway x 128 batch rows. bf16 MFMA 16x16x32, fp32 accum.
// x goes global->VGPR directly (A-frag layout is 16B-contiguous per lane:
// lane l needs 8 consecutive floats of one batch row). Only W1 is LDS-staged
// (reused by all 4 waves). Writes p TRANSPOSED as pT[P][B] so downstream
// kernels are coalesced.
// ---------------------------------------------------------------------------
__global__ __launch_bounds__(256) void k1_mlp(
    const float* __restrict__ x, const float* __restrict__ W1,
    const float* __restrict__ W2, float* __restrict__ pT)
{
    __shared__ unsigned short w1s[NW][NV + 8];  // bf16, padded leading dim
    __shared__ float w2s[NW];

    const int p   = blockIdx.x >> 7;     // pathway
    const int bt  = blockIdx.x & 127;    // batch tile
    const int tid = threadIdx.x;

    const int wave = tid >> 6;
    const int lane = tid & 63;
    const int l15  = lane & 15;
    const int lg   = lane >> 4;          // 0..3 (k-group)
    const int rowA = wave * 32;

    // ---- issue the dominant x stream FIRST (global->reg A fragments)
    const float* xr0 = x + (size_t)(bt * TB + rowA + l15) * (NP * NV)
                         + (size_t)p * NV + lg * 8;
    const float* xr1 = xr0 + (size_t)16 * (NP * NV);

    float4 xv[2][4][2];
    #pragma unroll
    for (int kk = 0; kk < 4; ++kk) {
        xv[0][kk][0] = *(const float4*)(xr0 + kk * 32);
        xv[0][kk][1] = *(const float4*)(xr0 + kk * 32 + 4);
        xv[1][kk][0] = *(const float4*)(xr1 + kk * 32);
        xv[1][kk][1] = *(const float4*)(xr1 + kk * 32 + 4);
    }

    // ---- stage W1[p] [64 x 128] fp32 -> bf16 LDS (coalesced)
    const float* w1g = W1 + (size_t)p * NW * NV;
    #pragma unroll
    for (int i = 0; i < 8; ++i) {
        int flat = i * 1024 + tid * 4;
        int r = flat >> 7, c = flat & 127;
        float4 v = *(const float4*)(w1g + flat);
        ushort4 b;
        b.x = f2bf(v.x); b.y = f2bf(v.y); b.z = f2bf(v.z); b.w = f2bf(v.w);
        *(ushort4*)(&w1s[r][c]) = b;
    }
    if (tid < NW) w2s[tid] = W2[p * NW + tid];

    // ---- pack x to bf16 fragments while LDS writes drain
    short8 afr[2][4];                    // [row-half][kk]
    #pragma unroll
    for (int kk = 0; kk < 4; ++kk) {
        afr[0][kk] = pack8(xv[0][kk][0], xv[0][kk][1]);
        afr[1][kk] = pack8(xv[1][kk][0], xv[1][kk][1]);
    }
    __syncthreads();                     // w1s ready

    // ---- MFMA: each wave owns 32 batch rows x all 64 w-cols
    f32x4 acc[2][4] = {};                // [row-frag][col-frag]
    #pragma unroll
    for (int kk = 0; kk < 4; ++kk) {     // K = 128 = 4 x 32
        const int ko = kk * 32 + lg * 8;
        #pragma unroll
        for (int f = 0; f < 4; ++f) {
            short8 bf = *(const short8*)(&w1s[f * 16 + l15][ko]);
            acc[0][f] = __builtin_amdgcn_mfma_f32_16x16x32_bf16(afr[0][kk], bf, acc[0][f], 0, 0, 0);
            acc[1][f] = __builtin_amdgcn_mfma_f32_16x16x32_bf16(afr[1][kk], bf, acc[1][f], 0, 0, 0);
        }
    }

    // ---- epilogue: leaky(h) @ W2 -> 16-lane reduce -> leaky -> store
    float w2v[4];
    #pragma unroll
    for (int f = 0; f < 4; ++f) w2v[f] = w2s[f * 16 + l15];

    #pragma unroll
    for (int rf = 0; rf < 2; ++rf) {
        float s0 = 0.f, s1 = 0.f, s2 = 0.f, s3 = 0.f;
        #pragma unroll
        for (int f = 0; f < 4; ++f) {
            f32x4 h = acc[rf][f];
            float h0 = h[0] >= 0.f ? h[0] : 0.2f * h[0];
            float h1 = h[1] >= 0.f ? h[1] : 0.2f * h[1];
            float h2 = h[2] >= 0.f ? h[2] : 0.2f * h[2];
            float h3 = h[3] >= 0.f ? h[3] : 0.2f * h[3];
            s0 += h0 * w2v[f]; s1 += h1 * w2v[f];
            s2 += h2 * w2v[f]; s3 += h3 * w2v[f];
        }
        // sum over the 64 w-columns: reduce across the 16 lanes of each lg-group
        #pragma unroll
        for (int m = 8; m >= 1; m >>= 1) {
            s0 += __shfl_xor(s0, m, 64);
            s1 += __shfl_xor(s1, m, 64);
            s2 += __shfl_xor(s2, m, 64);
            s3 += __shfl_xor(s3, m, 64);
        }
        if (l15 == 0) {
            s0 = s0 >= 0.f ? s0 : 0.2f * s0;
            s1 = s1 >= 0.f ? s1 : 0.2f * s1;
            s2 = s2 >= 0.f ? s2 : 0.2f * s2;
            s3 = s3 >= 0.f ? s3 : 0.2f * s3;
            float4 st = make_float4(s0, s1, s2, s3);
            int row = bt * TB + rowA + rf * 16 + lg * 4;
            *(float4*)(pT + (size_t)p * NB + row) = st;   // rows (l>>4)*4+reg
        }
    }
}

// ---------------------------------------------------------------------------
// Kernel 2: per-pathway batch mean / biased variance over pT[j][:]
// ---------------------------------------------------------------------------
__global__ __launch_bounds__(256) void k2_stats(
    const float* __restrict__ pT, float* __restrict__ meanv, float* __restrict__ varv)
{
    __shared__ double sb[4], ssb[4];
    const int j = blockIdx.x;
    const float4* col = (const float4*)(pT + (size_t)j * NB);
    double s = 0.0, ss = 0.0;
    for (int i = threadIdx.x; i < NB / 4; i += 256) {
        float4 v = col[i];
        s  += (double)v.x + (double)v.y + (double)v.z + (double)v.w;
        ss += (double)v.x * v.x + (double)v.y * v.y + (double)v.z * v.z + (double)v.w * v.w;
    }
    #pragma unroll
    for (int m = 32; m >= 1; m >>= 1) {
        s  += __shfl_xor(s, m, 64);
        ss += __shfl_xor(ss, m, 64);
    }
    const int wave = threadIdx.x >> 6, lane = threadIdx.x & 63;
    if (lane == 0) { sb[wave] = s; ssb[wave] = ss; }
    __syncthreads();
    if (threadIdx.x == 0) {
        double st  = sb[0] + sb[1] + sb[2] + sb[3];
        double sst = ssb[0] + ssb[1] + ssb[2] + ssb[3];
        double m = st / NB;
        meanv[j] = (float)m;
        varv[j]  = (float)(sst / NB - m * m);
    }
}

// ---------------------------------------------------------------------------
// Kernel 3: fold BN + global-L2-norm + disease layer into per-pathway affine.
//   Since sum_b (p-mean)=0:  ||pn||^2 = B * sum_j (g^2 var/(var+eps) + beta^2)
//   out[b] = sigmoid( sum_j p[b,j]*a_j + c ),
//     a_j = g_j*inv_j*Wd_j/norm,  c = sum_j (beta_j - m_j*g_j*inv_j)*Wd_j/norm + bd
// ---------------------------------------------------------------------------
__global__ __launch_bounds__(128) void k2b_coef(
    const float* __restrict__ meanv, const float* __restrict__ varv,
    const float* __restrict__ gamma, const float* __restrict__ beta,
    const float* __restrict__ Wd, const float* __restrict__ bd,
    float* __restrict__ a, float* __restrict__ c)
{
    __shared__ float nb[2], cb[2];
    const int j = threadIdx.x;           // 0..127
    float m  = meanv[j], v = varv[j], g = gamma[j], be = beta[j], wd = Wd[j];
    float inv = 1.0f / sqrtf(v + BN_EPS);
    float nn = g * g * v / (v + BN_EPS) + be * be;
    float cc = (be - m * inv * g) * wd;
    #pragma unroll
    for (int msk = 32; msk >= 1; msk >>= 1) {
        nn += __shfl_xor(nn, msk, 64);
        cc += __shfl_xor(cc, msk, 64);
    }
    const int wave = j >> 6, lane = j & 63;
    if (lane == 0) { nb[wave] = nn; cb[wave] = cc; }
    __syncthreads();
    float nnt = nb[0] + nb[1];
    float cct = cb[0] + cb[1];
    float norm = sqrtf((float)NB * nnt);
    a[j] = inv * g * wd / norm;
    if (j == 0) c[0] = cct / norm + bd[0];
}

// ---------------------------------------------------------------------------
// Kernel 4: out[b] = sigmoid( sum_j pT[j][b]*a_j + c )  (coalesced across b)
// ---------------------------------------------------------------------------
__global__ __launch_bounds__(256) void k3_out(
    const float* __restrict__ pT, const float* __restrict__ a,
    const float* __restrict__ c, float* __restrict__ out)
{
    __shared__ float as[NP];
    __shared__ float cs;
    if (threadIdx.x < NP) as[threadIdx.x] = a[threadIdx.x];
    if (threadIdx.x == 0) cs = c[0];
    __syncthreads();
    const int b = blockIdx.x * 256 + threadIdx.x;
    float z = cs;
    #pragma unroll 8
    for (int j = 0; j < NP; ++j) z += pT[(size_t)j * NB + b] * as[j];
    out[b] = 1.0f / (1.0f + expf(-z));
}

extern "C" void kernel_launch(void* const* d_in, const int* in_sizes, int n_in,
                              void* d_out, int out_size, void* d_ws, size_t ws_size,
                              hipStream_t stream)
{
    const float* x     = (const float*)d_in[0];
    const float* W1    = (const float*)d_in[1];
    const float* W2    = (const float*)d_in[2];
    const float* gamma = (const float*)d_in[3];
    const float* beta  = (const float*)d_in[4];
    const float* Wd    = (const float*)d_in[5];
    const float* bd    = (const float*)d_in[6];
    float* out = (float*)d_out;

    float* pT    = (float*)d_ws;               // [NP][NB] = 8 MB
    float* meanv = pT + (size_t)NP * NB;
    float* varv  = meanv + NP;
    float* av    = varv + NP;
    float* cv    = av + NP;

    hipLaunchKernelGGL(k1_mlp,  dim3(NP * (NB / TB)), dim3(256), 0, stream, x, W1, W2, pT);
    hipLaunchKernelGGL(k2_stats, dim3(NP),            dim3(256), 0, stream, pT, meanv, varv);
    hipLaunchKernelGGL(k2b_coef, dim3(1),             dim3(128), 0, stream,
                       meanv, varv, gamma, beta, Wd, bd, av, cv);
    hipLaunchKernelGGL(k3_out,  dim3(NB / 256),       dim3(256), 0, stream, pT, av, cv, out);
}